// Round 15
// baseline (89.382 us; speedup 1.0000x reference)
//
#include <hip/hip_runtime.h>
#include <math.h>

#define NN 4096
#define FF 128
#define DD 64
#define HH 4
#define NC 256   // HH*DD output columns
#define TSCALE 0.125f   // 2^-3 per table; P scaled 2^-6, cancels in num/den

typedef _Float16 f16x8 __attribute__((ext_vector_type(8)));
typedef _Float16 f16x4 __attribute__((ext_vector_type(4)));
typedef _Float16 f16x2 __attribute__((ext_vector_type(2)));
typedef float    f32x4 __attribute__((ext_vector_type(4)));

// ---------------------------------------------------------------------------
// Kernel 1: h = features @ W[h] via f16 LDS staging + v_dot2_f32_f16.
// Emits Bpack (f16 MFMA-B-fragment-ordered chunks) and SCALED f16 exp tables
// Es,Fs,En,Fn ([h][n], each x2^-3).
// ---------------------------------------------------------------------------
__global__ __launch_bounds__(256) void prep_kernel(
    const float* __restrict__ feats, const float* __restrict__ W,
    const float* __restrict__ ak, _Float16* __restrict__ Bpack,
    _Float16* __restrict__ Es, _Float16* __restrict__ Fs,
    _Float16* __restrict__ En, _Float16* __restrict__ Fn)
{
    __shared__ _Float16 Wth[64 * 136];
    __shared__ _Float16 fth[32 * 128];
    __shared__ float    hlds[32 * 65];
    const int t  = threadIdx.x;
    const int h  = blockIdx.y;
    const int n0 = blockIdx.x * 32;

    {
        const float* Wh = W + h * (FF * DD);
        #pragma unroll
        for (int j = 0; j < 8; ++j) {
            int idx = j * 256 + t;
            int f   = idx >> 4;
            int d4  = idx & 15;
            float4 v = ((const float4*)Wh)[idx];
            Wth[(d4 * 4 + 0) * 136 + f] = (_Float16)v.x;
            Wth[(d4 * 4 + 1) * 136 + f] = (_Float16)v.y;
            Wth[(d4 * 4 + 2) * 136 + f] = (_Float16)v.z;
            Wth[(d4 * 4 + 3) * 136 + f] = (_Float16)v.w;
        }
        #pragma unroll
        for (int j = 0; j < 4; ++j) {
            int idx = j * 256 + t;
            int r = idx >> 5, f4 = idx & 31;
            float4 v = ((const float4*)feats)[(size_t)(n0 + r) * 32 + f4];
            f16x4 hv = {(_Float16)v.x, (_Float16)v.y, (_Float16)v.z, (_Float16)v.w};
            *(f16x4*)&fth[r * 128 + f4 * 4] = hv;
        }
    }
    __syncthreads();

    const int d   = t & 63;
    const int wid = t >> 6;
    float acc[8];
    #pragma unroll
    for (int j = 0; j < 8; ++j) acc[j] = 0.f;

    union UW { f16x8 v; unsigned int u[4]; };
    for (int f8 = 0; f8 < 16; ++f8) {
        UW w8; w8.v = *(const f16x8*)&Wth[d * 136 + f8 * 8];
        #pragma unroll
        for (int j = 0; j < 8; ++j) {
            const int r = wid + 4 * j;
            UW fv; fv.v = *(const f16x8*)&fth[r * 128 + f8 * 8];
            #pragma unroll
            for (int p = 0; p < 4; ++p)
                acc[j] = __builtin_amdgcn_fdot2(
                    __builtin_bit_cast(f16x2, w8.u[p]),
                    __builtin_bit_cast(f16x2, fv.u[p]), acc[j], false);
        }
    }

    const float aks = ak[h * 128 + d];
    const float akn = ak[h * 128 + 64 + d];
    #pragma unroll
    for (int j = 0; j < 8; ++j) {
        const int r = wid + 4 * j;
        const float hv = acc[j];
        hlds[r * 65 + d] = hv;
        float v1 = hv * aks;
        float v2 = hv * akn;
        #pragma unroll
        for (int m = 32; m >= 1; m >>= 1) {
            v1 += __shfl_xor(v1, m, 64);
            v2 += __shfl_xor(v2, m, 64);
        }
        if (d == 0) {
            Es[h * NN + n0 + r] = (_Float16)(__expf(v1) * TSCALE);
            Fs[h * NN + n0 + r] = (_Float16)(__expf(0.2f * v1) * TSCALE);
            En[h * NN + n0 + r] = (_Float16)(__expf(v2) * TSCALE);
            Fn[h * NN + n0 + r] = (_Float16)(__expf(0.2f * v2) * TSCALE);
        }
    }
    __syncthreads();

    const int cb = t >> 6;
    const int l  = t & 63;
    const int lr = l & 15;
    const int kg = l >> 4;
    f16x8 v;
    #pragma unroll
    for (int j = 0; j < 8; ++j)
        v[j] = (_Float16)hlds[(kg * 8 + j) * 65 + cb * 16 + lr];
    *(f16x8*)(Bpack + ((size_t)(h * 128 + blockIdx.x)) * 2048 + (cb * 64 + l) * 8) = v;
}

// ---------------------------------------------------------------------------
// Kernel 2: fused MFMA attention, GROUP-OF-4 barrier cadence. Block = 4
// waves = 4 heads sharing rows n0..n0+31; adj read once. Per group of 4
// chunks: adj for group g+2 is ISSUED at the top of group g and only
// DRAINED by the barrier at the end of group g (lead ~4 chunk-times >
// HBM latency) -- the per-chunk __syncthreads vmcnt(0) drain was the
// 2 TB/s limiter in R12-R14. 4 int4/thread staged via 2x8KB LDS pair.
// B/tables 1-chunk-ahead named double-buffer (L2-resident).
// ---------------------------------------------------------------------------
__global__ __launch_bounds__(256, 4) void attn_kernel(
    const int* __restrict__ adj, const _Float16* __restrict__ Bpack,
    const _Float16* __restrict__ Es, const _Float16* __restrict__ Fs,
    const _Float16* __restrict__ En, const _Float16* __restrict__ Fn,
    _Float16* __restrict__ pacc, _Float16* __restrict__ pden, int ksplit)
{
    __shared__ _Float16 adjh[2][4][1024];   // [groupbuf][chunk][32r x 32m] = 16KB

    const int t  = threadIdx.x;
    const int h  = t >> 6;                  // wave = head
    const int l  = t & 63;
    const int lr = l & 15;
    const int kg = l >> 4;
    const int n0 = blockIdx.x * 32;
    const int s  = blockIdx.y;

    const int mstart = s * ksplit;
    const int nch    = ksplit >> 5;
    const int coff   = blockIdx.x & (nch - 1);
#define PCH(c) ((((c) + coff) & (nch - 1)))
#define CLC(c) ((c) < nch ? (c) : nch - 1)

    const _Float16 es0 = Es[h * NN + n0 + lr],      fs0 = Fs[h * NN + n0 + lr];
    const _Float16 es1 = Es[h * NN + n0 + 16 + lr], fs1 = Fs[h * NN + n0 + 16 + lr];
    const f16x2 es20 = {es0, es0}, fs20 = {fs0, fs0};
    const f16x2 es21 = {es1, es1}, fs21 = {fs1, fs1};

    const _Float16* __restrict__ EnB = En + (size_t)h * NN + mstart + kg * 8;
    const _Float16* __restrict__ FnB = Fn + (size_t)h * NN + mstart + kg * 8;
    const _Float16* __restrict__ bhead =
        Bpack + ((size_t)(h * 128) + (mstart >> 5)) * 2048 + l * 8;

    // staging: thread t -> row sr, quad mq (4 ints); swizzled LDS f16 offset
    const int sr = t >> 3;
    const int mq = t & 7;
    const int swoff = sr * 32 + (((mq >> 1) ^ (sr & 3)) << 3) + (mq & 1) * 4;
    const int* __restrict__ adjRow = adj + (size_t)(n0 + sr) * NN + mstart;

    // A-side LDS read offsets (granule swizzle; (lr+16)&3 == lr&3)
    const int perm = kg ^ (lr & 3);
    const int ro0  = lr * 32 + perm * 8;
    const int ro1  = (lr + 16) * 32 + perm * 8;

    f32x4 acc[2][4] = {};
    f32x4 dacc[2]   = {};
    f16x8 ones;
    #pragma unroll
    for (int j = 0; j < 8; ++j) ones[j] = (_Float16)1.0f;

    union U8 { f16x8 v; unsigned int u[4]; };

#define LDADJ(DST, C) do {                                                    \
        DST = ((const int4*)(adjRow + PCH(CLC(C)) * 32))[mq];                 \
    } while (0)
#define STADJ(PB, SUB, SRC) do {                                              \
        f16x4 _hv = {(_Float16)(SRC.x != 0), (_Float16)(SRC.y != 0),          \
                     (_Float16)(SRC.z != 0), (_Float16)(SRC.w != 0)};         \
        *(f16x4*)&adjh[PB][SUB][swoff] = _hv;                                 \
    } while (0)
#define LOADB(DST, C) do {                                                    \
        const _Float16* _b = bhead + (size_t)PCH(CLC(C)) * 2048;              \
        _Pragma("unroll")                                                     \
        for (int _cb = 0; _cb < 4; ++_cb)                                     \
            DST[_cb] = *(const f16x8*)(_b + _cb * 512);                       \
    } while (0)
#define LOADT(EQ, FQ, C) do {                                                 \
        EQ = *(const uint4*)(EnB + PCH(CLC(C)) * 32);                         \
        FQ = *(const uint4*)(FnB + PCH(CLC(C)) * 32);                         \
    } while (0)

#define CHUNK(C, PB, SUB, BCUR, BNXT, EQC, FQC, EQN, FQN) do {                \
        LOADB(BNXT, (C) + 1);                                                 \
        LOADT(EQN, FQN, (C) + 1);                                             \
        U8 AM0, AM1;                                                          \
        AM0.v = *(const f16x8*)&adjh[PB][SUB][ro0];                           \
        AM1.v = *(const f16x8*)&adjh[PB][SUB][ro1];                           \
        U8 A0, A1;                                                            \
        _Pragma("unroll")                                                     \
        for (int p = 0; p < 4; ++p) {                                         \
            const unsigned int eu = p == 0 ? EQC.x : p == 1 ? EQC.y : p == 2 ? EQC.z : EQC.w; \
            const unsigned int fu = p == 0 ? FQC.x : p == 1 ? FQC.y : p == 2 ? FQC.z : FQC.w; \
            const f16x2 en2 = __builtin_bit_cast(f16x2, eu);                  \
            const f16x2 fn2 = __builtin_bit_cast(f16x2, fu);                  \
            const f16x2 a20 = __builtin_bit_cast(f16x2, AM0.u[p]);            \
            const f16x2 a21 = __builtin_bit_cast(f16x2, AM1.u[p]);            \
            const f16x2 v0 = __builtin_elementwise_max(es20 * en2, fs20 * fn2) * a20; \
            const f16x2 v1 = __builtin_elementwise_max(es21 * en2, fs21 * fn2) * a21; \
            A0.u[p] = __builtin_bit_cast(unsigned int, v0);                   \
            A1.u[p] = __builtin_bit_cast(unsigned int, v1);                   \
        }                                                                     \
        __builtin_amdgcn_s_setprio(1);                                        \
        _Pragma("unroll")                                                     \
        for (int _cb = 0; _cb < 4; ++_cb) {                                   \
            acc[0][_cb] = __builtin_amdgcn_mfma_f32_16x16x32_f16(A0.v, BCUR[_cb], acc[0][_cb], 0, 0, 0); \
            acc[1][_cb] = __builtin_amdgcn_mfma_f32_16x16x32_f16(A1.v, BCUR[_cb], acc[1][_cb], 0, 0, 0); \
        }                                                                     \
        dacc[0] = __builtin_amdgcn_mfma_f32_16x16x32_f16(A0.v, ones, dacc[0], 0, 0, 0); \
        dacc[1] = __builtin_amdgcn_mfma_f32_16x16x32_f16(A1.v, ones, dacc[1], 0, 0, 0); \
        __builtin_amdgcn_s_setprio(0);                                        \
    } while (0)

    f16x8 B_0[4], B_1[4];
    uint4 eq0, fq0, eq1, fq1;
    int4  aA, aB, aC, aD;

    // ---- prologue: group 0 -> buf0; regs <- group 1; B/tables for chunk 0 --
    LDADJ(aA, 0); LDADJ(aB, 1); LDADJ(aC, 2); LDADJ(aD, 3);
    STADJ(0, 0, aA); STADJ(0, 1, aB); STADJ(0, 2, aC); STADJ(0, 3, aD);
    LDADJ(aA, 4); LDADJ(aB, 5); LDADJ(aC, 6); LDADJ(aD, 7);
    LOADB(B_0, 0);
    LOADT(eq0, fq0, 0);
    __syncthreads();

    const int ngrp = nch >> 2;
    for (int g = 0; g < ngrp; ++g) {
        const int nb = (g + 1) & 1;
        const int pb = g & 1;
        // stage group g+1 (regs loaded at group g-1); issue group g+2 loads NOW
        STADJ(nb, 0, aA); STADJ(nb, 1, aB); STADJ(nb, 2, aC); STADJ(nb, 3, aD);
        LDADJ(aA, 4 * g + 8);  LDADJ(aB, 4 * g + 9);
        LDADJ(aC, 4 * g + 10); LDADJ(aD, 4 * g + 11);
        __builtin_amdgcn_sched_barrier(0);   // pin load issue before compute

        CHUNK(4 * g + 0, pb, 0, B_0, B_1, eq0, fq0, eq1, fq1);
        CHUNK(4 * g + 1, pb, 1, B_1, B_0, eq1, fq1, eq0, fq0);
        CHUNK(4 * g + 2, pb, 2, B_0, B_1, eq0, fq0, eq1, fq1);
        CHUNK(4 * g + 3, pb, 3, B_1, B_0, eq1, fq1, eq0, fq0);

        __syncthreads();   // drains group g+2 loads: lead = 4 chunk-times
    }
#undef CHUNK
#undef LOADT
#undef LOADB
#undef STADJ
#undef LDADJ
#undef CLC
#undef PCH

    #pragma unroll
    for (int rb = 0; rb < 2; ++rb) {
        #pragma unroll
        for (int r = 0; r < 4; ++r) {
            const int row = n0 + rb * 16 + kg * 4 + r;
            #pragma unroll
            for (int cb = 0; cb < 4; ++cb)
                pacc[((size_t)(s * NN + row)) * NC + h * 64 + cb * 16 + lr] =
                    (_Float16)acc[rb][cb][r];
            if (lr == 0)
                pden[(s * NN + row) * 4 + h] = (_Float16)dacc[rb][r];
        }
    }
}

// ---------------------------------------------------------------------------
// Kernel 3: reduce f16 splits in f32, normalize, ReLU. 8 rows/block.
// ---------------------------------------------------------------------------
__global__ __launch_bounds__(256) void finalize_kernel(
    const _Float16* __restrict__ pacc, const _Float16* __restrict__ pden,
    float* __restrict__ out, int nsplit)
{
    const int t = threadIdx.x;
    const int n = blockIdx.x * 8 + (t >> 5);
    const int q = t & 31;              // 8-col group
    const int h = q >> 3;

    float a[8];
    #pragma unroll
    for (int i = 0; i < 8; ++i) a[i] = 0.f;
    float d = 0.f;
    for (int s = 0; s < nsplit; ++s) {
        const f16x8 v = *(const f16x8*)&pacc[((size_t)(s * NN + n)) * NC + q * 8];
        #pragma unroll
        for (int i = 0; i < 8; ++i) a[i] += (float)v[i];
        d += (float)pden[(s * NN + n) * 4 + h];
    }
    const float inv = (d > 0.f) ? 1.0f / d : 0.f;
    f32x4 o0, o1;
    #pragma unroll
    for (int i = 0; i < 4; ++i) {
        const float v0 = a[i] * inv;
        const float v1 = a[i + 4] * inv;
        o0[i] = v0 > 0.f ? v0 : 0.f;
        o1[i] = v1 > 0.f ? v1 : 0.f;
    }
    float* po = &out[(size_t)n * NC + q * 8];
    *(f32x4*)po       = o0;
    *(f32x4*)(po + 4) = o1;
}

// ---------------------------------------------------------------------------
extern "C" void kernel_launch(void* const* d_in, const int* in_sizes, int n_in,
                              void* d_out, int out_size, void* d_ws, size_t ws_size,
                              hipStream_t stream)
{
    const int*   adj   = (const int*)d_in[0];
    const float* feats = (const float*)d_in[1];
    const float* W     = (const float*)d_in[2];
    const float* ak    = (const float*)d_in[3];
    float*       out   = (float*)d_out;

    char* ws = (char*)d_ws;
    _Float16* Bpack = (_Float16*)ws;                                  // 2 MB
    _Float16* Es    = (_Float16*)(ws + (2ull << 20));                 // 32 KB
    _Float16* Fs    = (_Float16*)(ws + (2ull << 20) + (1 << 15));     // 32 KB
    _Float16* En    = (_Float16*)(ws + (2ull << 20) + (2 << 15));     // 32 KB
    _Float16* Fn    = (_Float16*)(ws + (2ull << 20) + (3 << 15));     // 32 KB
    _Float16* pden  = (_Float16*)(ws + (2ull << 20) + (4 << 15));     // <=512 KB
    _Float16* pacc  = (_Float16*)(ws + (3ull << 20));                 // nsplit*2 MB

    int nsplit = 16;
    while (nsplit > 1 && ws_size < (3ull << 20) + (size_t)nsplit * (2ull << 20))
        nsplit >>= 1;
    const int ksplit = NN / nsplit;

    prep_kernel<<<dim3(128, 4), 256, 0, stream>>>(feats, W, ak, Bpack, Es, Fs, En, Fn);
    attn_kernel<<<dim3(128, nsplit), 256, 0, stream>>>(adj, Bpack, Es, Fs, En, Fn,
                                                       pacc, pden, ksplit);
    finalize_kernel<<<512, 256, 0, stream>>>(pacc, pden, out, nsplit);
}

// Round 16
// 59.810 us; speedup vs baseline: 1.4944x; 1.4944x over previous
//
#include <hip/hip_runtime.h>
#include <math.h>

#define NN 4096
#define FF 128
#define DD 64
#define HH 4
#define NC 256  // HH*DD output columns

typedef _Float16 f16x8 __attribute__((ext_vector_type(8)));
typedef _Float16 f16x4 __attribute__((ext_vector_type(4)));
typedef _Float16 f16x2 __attribute__((ext_vector_type(2)));
typedef float    f32x4 __attribute__((ext_vector_type(4)));

// ---------------------------------------------------------------------------
// Kernel 0: adjacency int32 -> bitmask, COALESCED + LDS repack (no ballots).
// Block = 2 rows (8192 ints, 32KB). Phase 1: 8 iters of {coalesced int4 load
// (1KB/instr = 8 lines shared by 8 lanes), pack 4 flags into a u32 of 0/1
// bytes, LDS write at pad-swizzled index s+(s>>3)}. Phase 2: thread t reads
// 8 u32 at stride-9 (conflict-free), packs 32 flags -> adjw word, contiguous
// 1KB store per block. adjw[n*128+w] bit b = (adj[n][w*32+b] != 0).
// ---------------------------------------------------------------------------
__global__ __launch_bounds__(256) void adjbits_kernel(
    const int* __restrict__ adj, unsigned int* __restrict__ adjw)
{
    __shared__ unsigned int fl[2304];   // 2048 logical u32 + stride-9 pad
    const int t = threadIdx.x;
    const size_t e0 = (size_t)blockIdx.x * 8192;   // first element of 2 rows

    #pragma unroll
    for (int i = 0; i < 8; ++i) {
        const int4 v = ((const int4*)adj)[e0 / 4 + i * 256 + t];
        const unsigned int b = (v.x != 0 ? 0x1u : 0u) |
                               (v.y != 0 ? 0x100u : 0u) |
                               (v.z != 0 ? 0x10000u : 0u) |
                               (v.w != 0 ? 0x1000000u : 0u);
        const int s = i * 256 + t;
        fl[s + (s >> 3)] = b;
    }
    __syncthreads();

    unsigned int w = 0;
    #pragma unroll
    for (int k = 0; k < 8; ++k) {
        const unsigned int g = fl[t * 9 + k];
        const unsigned int nib = (g | (g >> 7) | (g >> 14) | (g >> 21)) & 0xFu;
        w |= nib << (k * 4);
    }
    adjw[blockIdx.x * 256 + t] = w;
}

// ---------------------------------------------------------------------------
// Kernel 1: h = features @ W[h] via f16 LDS staging + v_dot2_f32_f16.
// Emits Bpack (f16 MFMA-B-fragment-ordered chunks: Bpack[h][chunk][cb][lane][8],
// 4KB contiguous per 64d x 32m chunk) and f16 exp tables Es,Fs,En,Fn ([h][n]).
// ---------------------------------------------------------------------------
__global__ __launch_bounds__(256) void prep_kernel(
    const float* __restrict__ feats, const float* __restrict__ W,
    const float* __restrict__ ak, _Float16* __restrict__ Bpack,
    _Float16* __restrict__ Es, _Float16* __restrict__ Fs,
    _Float16* __restrict__ En, _Float16* __restrict__ Fn)
{
    __shared__ _Float16 Wth[64 * 136];
    __shared__ _Float16 fth[32 * 128];
    __shared__ float    hlds[32 * 65];
    const int t  = threadIdx.x;
    const int h  = blockIdx.y;
    const int n0 = blockIdx.x * 32;

    {
        const float* Wh = W + h * (FF * DD);
        #pragma unroll
        for (int j = 0; j < 8; ++j) {
            int idx = j * 256 + t;
            int f   = idx >> 4;
            int d4  = idx & 15;
            float4 v = ((const float4*)Wh)[idx];
            Wth[(d4 * 4 + 0) * 136 + f] = (_Float16)v.x;
            Wth[(d4 * 4 + 1) * 136 + f] = (_Float16)v.y;
            Wth[(d4 * 4 + 2) * 136 + f] = (_Float16)v.z;
            Wth[(d4 * 4 + 3) * 136 + f] = (_Float16)v.w;
        }
        #pragma unroll
        for (int j = 0; j < 4; ++j) {
            int idx = j * 256 + t;
            int r = idx >> 5, f4 = idx & 31;
            float4 v = ((const float4*)feats)[(size_t)(n0 + r) * 32 + f4];
            f16x4 hv = {(_Float16)v.x, (_Float16)v.y, (_Float16)v.z, (_Float16)v.w};
            *(f16x4*)&fth[r * 128 + f4 * 4] = hv;
        }
    }
    __syncthreads();

    const int d   = t & 63;
    const int wid = t >> 6;
    float acc[8];
    #pragma unroll
    for (int j = 0; j < 8; ++j) acc[j] = 0.f;

    union UW { f16x8 v; unsigned int u[4]; };
    for (int f8 = 0; f8 < 16; ++f8) {
        UW w8; w8.v = *(const f16x8*)&Wth[d * 136 + f8 * 8];
        #pragma unroll
        for (int j = 0; j < 8; ++j) {
            const int r = wid + 4 * j;
            UW fv; fv.v = *(const f16x8*)&fth[r * 128 + f8 * 8];
            #pragma unroll
            for (int p = 0; p < 4; ++p)
                acc[j] = __builtin_amdgcn_fdot2(
                    __builtin_bit_cast(f16x2, w8.u[p]),
                    __builtin_bit_cast(f16x2, fv.u[p]), acc[j], false);
        }
    }

    const float aks = ak[h * 128 + d];
    const float akn = ak[h * 128 + 64 + d];
    #pragma unroll
    for (int j = 0; j < 8; ++j) {
        const int r = wid + 4 * j;
        const float hv = acc[j];
        hlds[r * 65 + d] = hv;
        float v1 = hv * aks;
        float v2 = hv * akn;
        #pragma unroll
        for (int m = 32; m >= 1; m >>= 1) {
            v1 += __shfl_xor(v1, m, 64);
            v2 += __shfl_xor(v2, m, 64);
        }
        if (d == 0) {
            Es[h * NN + n0 + r] = (_Float16)__expf(v1);
            Fs[h * NN + n0 + r] = (_Float16)__expf(0.2f * v1);
            En[h * NN + n0 + r] = (_Float16)__expf(v2);
            Fn[h * NN + n0 + r] = (_Float16)__expf(0.2f * v2);
        }
    }
    __syncthreads();

    const int cb = t >> 6;
    const int l  = t & 63;
    const int lr = l & 15;
    const int kg = l >> 4;
    f16x8 v;
    #pragma unroll
    for (int j = 0; j < 8; ++j)
        v[j] = (_Float16)hlds[(kg * 8 + j) * 65 + cb * 16 + lr];
    *(f16x8*)(Bpack + ((size_t)(h * 128 + blockIdx.x)) * 2048 + (cb * 64 + l) * 8) = v;
}

// ---------------------------------------------------------------------------
// Kernel 2: MFMA attention (R9/R7 proven form). Block = 4 waves (one head,
// 128 rows). Chunk-order ROTATED per block; dense Bpack chunk (4KB) staged
// to LDS double-buffer, 1 barrier/chunk, B staged 2 chunks ahead, tables
// prefetched 1 ahead in regs. A = mask ? max(Es*En, Fs*Fn) : 0 (packed f16).
// mfma_f32_16x16x32_f16; C layout col=lane&15, row=(lane>>4)*4+reg.
// ---------------------------------------------------------------------------
__global__ __launch_bounds__(256, 4) void attn_kernel(
    const unsigned int* __restrict__ adjw, const _Float16* __restrict__ Bpack,
    const _Float16* __restrict__ Es, const _Float16* __restrict__ Fs,
    const _Float16* __restrict__ En, const _Float16* __restrict__ Fn,
    float* __restrict__ pacc, float* __restrict__ pden, int ksplit)
{
    __shared__ _Float16 Blds[2][2048];   // 2 x 4KB double buffer

    const int t  = threadIdx.x;
    const int w  = t >> 6;
    const int l  = t & 63;
    const int lr = l & 15;
    const int kg = l >> 4;
    const int h  = blockIdx.y;
    const int s  = blockIdx.z;
    const int n0 = blockIdx.x * 128 + w * 32;

    const int mstart = s * ksplit;
    const int nchunk = ksplit >> 5;
    const int ncq    = nchunk >> 2;
    const int coff   = blockIdx.x & (ncq - 1);
    const int wb     = mstart >> 5;

#define PC(c) (((((c) >> 2) + coff) & (ncq - 1)) * 4 + ((c) & 3))

    const _Float16 es0 = Es[h * NN + n0 + lr],      fs0 = Fs[h * NN + n0 + lr];
    const _Float16 es1 = Es[h * NN + n0 + 16 + lr], fs1 = Fs[h * NN + n0 + 16 + lr];
    const f16x2 es20 = {es0, es0}, fs20 = {fs0, fs0};
    const f16x2 es21 = {es1, es1}, fs21 = {fs1, fs1};

    const _Float16* __restrict__ EnB = En + (size_t)h * NN;
    const _Float16* __restrict__ FnB = Fn + (size_t)h * NN;
    const int row0 = n0 + lr, row1 = n0 + 16 + lr;

    const _Float16* __restrict__ bp =
        Bpack + ((size_t)(h * 128) + wb) * 2048 + t * 8;

    f32x4 acc[2][4] = {};
    f32x4 dacc[2]   = {};
    f16x8 ones;
    #pragma unroll
    for (int j = 0; j < 8; ++j) ones[j] = (_Float16)1.0f;

    union U8 { f16x8 v; unsigned int u[4]; };

    // ---- prologue ----
    uint4 sreg = *(const uint4*)(bp + (size_t)PC(0) * 2048);
    *(uint4*)&Blds[0][t * 8] = sreg;
    sreg = *(const uint4*)(bp + (size_t)PC(1) * 2048);
    uint4 enqc = *(const uint4*)(EnB + mstart + PC(0) * 32 + kg * 8);
    uint4 fnqc = *(const uint4*)(FnB + mstart + PC(0) * 32 + kg * 8);
    __syncthreads();

    for (int cq = 0; cq < ncq; ++cq) {
        const int cqp = (cq + coff) & (ncq - 1);
        const uint4 mk0 = *(const uint4*)&adjw[(size_t)row0 * 128 + wb + cqp * 4];
        const uint4 mk1 = *(const uint4*)&adjw[(size_t)row1 * 128 + wb + cqp * 4];

        #pragma unroll
        for (int ci = 0; ci < 4; ++ci) {
            const int c = cq * 4 + ci;

            uint4 nreg;
            {
                const int cn = (c + 2 < nchunk) ? c + 2 : c;
                nreg = *(const uint4*)(bp + (size_t)PC(cn) * 2048);
            }
            if (c + 1 < nchunk)
                *(uint4*)&Blds[(c + 1) & 1][t * 8] = sreg;
            uint4 enq_n, fnq_n;
            {
                const int cn = (c + 1 < nchunk) ? c + 1 : c;
                enq_n = *(const uint4*)(EnB + mstart + PC(cn) * 32 + kg * 8);
                fnq_n = *(const uint4*)(FnB + mstart + PC(cn) * 32 + kg * 8);
            }

            const unsigned int b0 =
                (ci == 0 ? mk0.x : ci == 1 ? mk0.y : ci == 2 ? mk0.z : mk0.w) >> (kg * 8);
            const unsigned int b1 =
                (ci == 0 ? mk1.x : ci == 1 ? mk1.y : ci == 2 ? mk1.z : mk1.w) >> (kg * 8);
            U8 A0, A1;
            #pragma unroll
            for (int p = 0; p < 4; ++p) {
                const unsigned int eu = p == 0 ? enqc.x : p == 1 ? enqc.y : p == 2 ? enqc.z : enqc.w;
                const unsigned int fu = p == 0 ? fnqc.x : p == 1 ? fnqc.y : p == 2 ? fnqc.z : fnqc.w;
                const f16x2 en2 = __builtin_bit_cast(f16x2, eu);
                const f16x2 fn2 = __builtin_bit_cast(f16x2, fu);
                const f16x2 v0 = __builtin_elementwise_max(es20 * en2, fs20 * fn2);
                const f16x2 v1 = __builtin_elementwise_max(es21 * en2, fs21 * fn2);
                const unsigned int mm0 = (((b0 >> (2 * p)) & 1u) ? 0x0000FFFFu : 0u)
                                       | (((b0 >> (2 * p + 1)) & 1u) ? 0xFFFF0000u : 0u);
                const unsigned int mm1 = (((b1 >> (2 * p)) & 1u) ? 0x0000FFFFu : 0u)
                                       | (((b1 >> (2 * p + 1)) & 1u) ? 0xFFFF0000u : 0u);
                A0.u[p] = __builtin_bit_cast(unsigned int, v0) & mm0;
                A1.u[p] = __builtin_bit_cast(unsigned int, v1) & mm1;
            }

            __builtin_amdgcn_s_setprio(1);
            #pragma unroll
            for (int cb = 0; cb < 4; ++cb) {
                const f16x8 Bf = *(const f16x8*)&Blds[c & 1][(cb * 64 + l) * 8];
                acc[0][cb] = __builtin_amdgcn_mfma_f32_16x16x32_f16(A0.v, Bf, acc[0][cb], 0, 0, 0);
                acc[1][cb] = __builtin_amdgcn_mfma_f32_16x16x32_f16(A1.v, Bf, acc[1][cb], 0, 0, 0);
            }
            dacc[0] = __builtin_amdgcn_mfma_f32_16x16x32_f16(A0.v, ones, dacc[0], 0, 0, 0);
            dacc[1] = __builtin_amdgcn_mfma_f32_16x16x32_f16(A1.v, ones, dacc[1], 0, 0, 0);
            __builtin_amdgcn_s_setprio(0);

            __syncthreads();
            sreg = nreg;
            enqc = enq_n;
            fnqc = fnq_n;
        }
    }
#undef PC

    #pragma unroll
    for (int rb = 0; rb < 2; ++rb) {
        #pragma unroll
        for (int r = 0; r < 4; ++r) {
            const int row = n0 + rb * 16 + kg * 4 + r;
            #pragma unroll
            for (int cb = 0; cb < 4; ++cb)
                pacc[((size_t)(s * NN + row)) * NC + h * 64 + cb * 16 + lr] = acc[rb][cb][r];
            if (lr == 0)
                pden[(s * NN + row) * 4 + h] = dacc[rb][r];
        }
    }
}

// ---------------------------------------------------------------------------
// Kernel 3: reduce splits, normalize, ReLU. float4 per thread, 4 rows/block.
// ---------------------------------------------------------------------------
__global__ __launch_bounds__(256) void finalize_kernel(
    const float* __restrict__ pacc, const float* __restrict__ pden,
    float* __restrict__ out, int nsplit)
{
    const int t = threadIdx.x;
    const int n = blockIdx.x * 4 + (t >> 6);
    const int q = t & 63;
    const int h = q >> 4;

    f32x4 a = {0.f, 0.f, 0.f, 0.f};
    float d = 0.f;
    for (int s = 0; s < nsplit; ++s) {
        a += *(const f32x4*)&pacc[((size_t)(s * NN + n)) * NC + q * 4];
        d += pden[(s * NN + n) * 4 + h];
    }
    f32x4 o;
    const float inv = (d > 0.f) ? 1.0f / d : 0.f;
    #pragma unroll
    for (int i = 0; i < 4; ++i) {
        const float v = a[i] * inv;
        o[i] = v > 0.f ? v : 0.f;
    }
    *(f32x4*)&out[(size_t)n * NC + q * 4] = o;
}

// ---------------------------------------------------------------------------
extern "C" void kernel_launch(void* const* d_in, const int* in_sizes, int n_in,
                              void* d_out, int out_size, void* d_ws, size_t ws_size,
                              hipStream_t stream)
{
    const int*   adj   = (const int*)d_in[0];
    const float* feats = (const float*)d_in[1];
    const float* W     = (const float*)d_in[2];
    const float* ak    = (const float*)d_in[3];
    float*       out   = (float*)d_out;

    char* ws = (char*)d_ws;
    unsigned int* adjw  = (unsigned int*)ws;                          // 2 MB
    _Float16*     Bpack = (_Float16*)(ws + (2ull << 20));             // 2 MB
    _Float16*     Es    = (_Float16*)(ws + (4ull << 20));             // 32 KB
    _Float16*     Fs    = (_Float16*)(ws + (4ull << 20) + (1 << 16)); // 32 KB
    _Float16*     En    = (_Float16*)(ws + (4ull << 20) + (2 << 16)); // 32 KB
    _Float16*     Fn    = (_Float16*)(ws + (4ull << 20) + (3 << 16)); // 32 KB
    float*        pden  = (float*)(ws + (4ull << 20) + (4 << 16));    // <=512 KB
    float*        pacc  = (float*)(ws + (5ull << 20));                // nsplit*4 MB

    int nsplit = 8;
    while (nsplit > 1 && ws_size < (5ull << 20) + (size_t)nsplit * (4ull << 20))
        nsplit >>= 1;
    const int ksplit = NN / nsplit;

    adjbits_kernel<<<2048, 256, 0, stream>>>(adj, adjw);
    prep_kernel<<<dim3(128, 4), 256, 0, stream>>>(feats, W, ak, Bpack, Es, Fs, En, Fn);
    attn_kernel<<<dim3(32, 4, nsplit), 256, 0, stream>>>(adjw, Bpack, Es, Fs, En, Fn,
                                                         pacc, pden, ksplit);
    finalize_kernel<<<1024, 256, 0, stream>>>(pacc, pden, out, nsplit);
}